// Round 1
// baseline (214.400 us; speedup 1.0000x reference)
//
#include <hip/hip_runtime.h>

// ColorHistogramLoss: B=32, C=3, H=W=512, BINS=64.
// loss = mean_{B×(C·BINS)} | hist(input) - hist(target) |, hist normalized by N=H*W.
// Strategy: fused signed-diff histogram (LDS privatized, global atomic merge),
// then a one-block abs-sum reduction. Pure HBM-bound: 201 MB read -> ~32 us floor.

#define BINS 64
#define PLANES 96          // B*C
#define PLANE_F4 65536     // 512*512/4
#define SEGS 32            // segments per plane
#define SEG_F4 2048        // PLANE_F4/SEGS
#define TPB 256
#define F4T 8              // SEG_F4/TPB float4 per thread per tensor

__device__ __forceinline__ void bump(int* lh, float v, int inc) {
    // searchsorted(linspace(-1,1,64), v, 'right')-1  ==  floor((v+1)*63/2),
    // with v<-1 invalid (skip) and v>=1 clamped to bin 63.
    int bin = (int)floorf((v + 1.0f) * 31.5f);
    if (bin >= 0) {
        bin = bin > 63 ? 63 : bin;
        atomicAdd(&lh[bin], inc);
    }
}

__global__ __launch_bounds__(TPB) void hist_diff_kernel(
        const float4* __restrict__ in4, const float4* __restrict__ tg4,
        int* __restrict__ gdiff) {
    __shared__ int lh[BINS];
    const int tid = threadIdx.x;
    if (tid < BINS) lh[tid] = 0;
    __syncthreads();

    const int plane = blockIdx.x >> 5;           // /SEGS
    const int seg   = blockIdx.x & (SEGS - 1);
    const long base = (long)plane * PLANE_F4 + (long)seg * SEG_F4 + tid;

    float4 a[F4T];
    // input chunk: +1
#pragma unroll
    for (int k = 0; k < F4T; ++k) a[k] = in4[base + k * TPB];
#pragma unroll
    for (int k = 0; k < F4T; ++k) {
        bump(lh, a[k].x, 1); bump(lh, a[k].y, 1);
        bump(lh, a[k].z, 1); bump(lh, a[k].w, 1);
    }
    // target chunk: -1
#pragma unroll
    for (int k = 0; k < F4T; ++k) a[k] = tg4[base + k * TPB];
#pragma unroll
    for (int k = 0; k < F4T; ++k) {
        bump(lh, a[k].x, -1); bump(lh, a[k].y, -1);
        bump(lh, a[k].z, -1); bump(lh, a[k].w, -1);
    }

    __syncthreads();
    if (tid < BINS) {
        int v = lh[tid];
        if (v != 0) atomicAdd(&gdiff[plane * BINS + tid], v);
    }
}

__global__ __launch_bounds__(TPB) void reduce_abs_kernel(
        const int* __restrict__ gdiff, float* __restrict__ out) {
    int s = 0;
    for (int i = threadIdx.x; i < PLANES * BINS; i += TPB) {
        int v = gdiff[i];
        s += (v < 0) ? -v : v;
    }
    // wave64 butterfly
#pragma unroll
    for (int off = 32; off > 0; off >>= 1) s += __shfl_down(s, off, 64);
    __shared__ int ws[TPB / 64];
    const int wid  = threadIdx.x >> 6;
    const int lane = threadIdx.x & 63;
    if (lane == 0) ws[wid] = s;
    __syncthreads();
    if (threadIdx.x == 0) {
        int total = 0;
#pragma unroll
        for (int w = 0; w < TPB / 64; ++w) total += ws[w];
        // loss = total / N / (B*C*BINS); total < 2^24 so exact in fp32
        out[0] = (float)total * (1.0f / (262144.0f * 6144.0f));
    }
}

extern "C" void kernel_launch(void* const* d_in, const int* in_sizes, int n_in,
                              void* d_out, int out_size, void* d_ws, size_t ws_size,
                              hipStream_t stream) {
    const float4* inp = (const float4*)d_in[0];
    const float4* tgt = (const float4*)d_in[1];
    int* gdiff = (int*)d_ws;   // 96*64 signed counts, 24 KiB

    hipMemsetAsync(gdiff, 0, PLANES * BINS * sizeof(int), stream);
    hist_diff_kernel<<<PLANES * SEGS, TPB, 0, stream>>>(inp, tgt, gdiff);
    reduce_abs_kernel<<<1, TPB, 0, stream>>>(gdiff, (float*)d_out);
}